// Round 4
// baseline (248.358 us; speedup 1.0000x reference)
//
#include <hip/hip_runtime.h>
#include <hip/hip_cooperative_groups.h>
#include <math.h>

namespace cg = cooperative_groups;

#define BB 32
#define NN 1000
#define CC 81
#define MAX_INST 100
#define MIN_CONF 0.7f
#define NMS_THRESH 0.3f
#define MCAP 1024     // per-batch candidate capacity (>= NN)
#define RCHUNK 128    // suppression-matrix rows per chunk
#define WMAX 16       // 64-bit words per keep row (1024/64)
#define NBLK 512
#define NTHR 256

// glist entry: 8 floats = {y1,x1,y2,x2,score,cls,orig_idx,pad}

__global__ __launch_bounds__(NTHR) void fused_detection_kernel(
    const float* __restrict__ rois,      // B,N,4
    const float* __restrict__ probs,     // B,N,C
    const float* __restrict__ deltas,    // B,N,C,4
    const float* __restrict__ std_dev,   // 4
    int* __restrict__ gcnt,              // 32 counters
    float* __restrict__ glist,           // B x MCAP x 8
    float* __restrict__ out)             // B,MAX_INST,6
{
  cg::grid_group grid = cg::this_grid();
  const int t    = threadIdx.x;
  const int blk  = blockIdx.x;
  const int gtid = blk * NTHR + t;

  // LDS (~48 KB -> >=3 blocks/CU co-resident; 512 blocks fit on 256 CUs)
  __shared__ float cscore[MCAP];
  __shared__ int   cidx[MCAP];
  __shared__ float sy1[MCAP], sx1[MCAP], sy2[MCAP], sx2[MCAP];
  __shared__ int   scls[MCAP];
  __shared__ float sscr[MCAP];
  __shared__ unsigned long long rows[RCHUNK][WMAX];
  __shared__ unsigned long long keepw[WMAX];

  // ---- phase 0: zero counters + output (d_out/d_ws poisoned 0xAA) ----
  if (gtid < BB) gcnt[gtid] = 0;
  {
    float4* o4 = (float4*)out;
    const int n4 = BB * MAX_INST * 6 / 4;   // 4800 float4s
    if (gtid < n4) o4[gtid] = make_float4(0.f, 0.f, 0.f, 0.f);
  }
  grid.sync();

  // ---- phase 1: one wave per ROI (grid-stride), argmax + decode + append ----
  const int lane  = t & 63;
  const int gwave = gtid >> 6;               // 0..2047
  for (int wg = gwave; wg < BB * NN; wg += (NBLK * NTHR) / 64) {
    const float* p = probs + (size_t)wg * CC;
    float v = p[lane];                       // classes 0..63
    int   c = lane;
    if (lane + 64 < CC) {                    // classes 64..80
      float v2 = p[lane + 64];
      if (v2 > v) { v = v2; c = lane + 64; } // lower class wins ties
    }
    for (int off = 32; off; off >>= 1) {     // first-occurrence argmax
      float vo = __shfl_down(v, off);
      int   co = __shfl_down(c, off);
      if (vo > v || (vo == v && co < c)) { v = vo; c = co; }
    }
    if (lane == 0 && c > 0 && v >= MIN_CONF) {
      float4 dd = *(const float4*)(deltas + ((size_t)wg * CC + c) * 4);
      float4 r4 = *(const float4*)(rois + (size_t)wg * 4);
      float dy = dd.x * std_dev[0], dx = dd.y * std_dev[1];
      float dh = dd.z * std_dev[2], dw = dd.w * std_dev[3];
      float h = r4.z - r4.x, w = r4.w - r4.y;
      float cy = r4.x + 0.5f * h + dy * h;
      float cx = r4.y + 0.5f * w + dx * w;
      h *= expf(dh); w *= expf(dw);
      float y1 = cy - 0.5f * h, x1 = cx - 0.5f * w;
      float y2 = y1 + h,        x2 = x1 + w;
      y1 = fminf(fmaxf(y1, 0.f), 1.f); x1 = fminf(fmaxf(x1, 0.f), 1.f);
      y2 = fminf(fmaxf(y2, 0.f), 1.f); x2 = fminf(fmaxf(x2, 0.f), 1.f);
      int b = wg / NN, n = wg - b * NN;
      int pos = atomicAdd(&gcnt[b], 1);      // device-scope
      float4* o = (float4*)(glist + ((size_t)b * MCAP + pos) * 8);
      o[0] = make_float4(y1, x1, y2, x2);
      o[1] = make_float4(v, (float)c, (float)n, 0.f);
    }
  }
  __threadfence();
  grid.sync();

  // ---- phase 2: blocks 0..31 — stable rank sort + ballot NMS + compact ----
  if (blk >= BB) return;
  const int b = blk;
  const int M = gcnt[b];
  const int W = (M + 63) >> 6;
  const float* base = glist + (size_t)b * MCAP * 8;

  for (int e = t; e < M; e += NTHR) {
    const float4 s = ((const float4*)(base + (size_t)e * 8))[1];
    cscore[e] = s.x; cidx[e] = (int)s.z;
  }
  __syncthreads();

  // rank = stable-argsort position (score desc, orig idx asc); scatter sorted
  for (int e = t; e < M; e += NTHR) {
    const float4 a = ((const float4*)(base + (size_t)e * 8))[0];
    const float4 s = ((const float4*)(base + (size_t)e * 8))[1];
    float sc = s.x; int oi = (int)s.z;
    int r = 0;
    for (int j = 0; j < M; ++j) {
      float sj = cscore[j]; int ij = cidx[j];
      if (sj > sc || (sj == sc && ij < oi)) ++r;
    }
    sy1[r] = a.x; sx1[r] = a.y; sy2[r] = a.z; sx2[r] = a.w;
    scls[r] = (int)s.y; sscr[r] = sc;
  }
  if (t < WMAX) {
    unsigned long long kw = 0ULL;
    int nb = M - t * 64;
    if (nb > 0) kw = (nb >= 64) ? ~0ULL : ((1ULL << nb) - 1ULL);
    keepw[t] = kw;
  }
  __syncthreads();

  // chunked suppression matrix (ballot rows) + wave-serial keep propagation
  const int wv = t >> 6;
  for (int c0 = 0; c0 < M; c0 += RCHUNK) {
    int R = min(RCHUNK, M - c0);
    for (int task = wv; task < R * W; task += 4) {
      int i = c0 + task / W;
      int w = task % W;
      int j = w * 64 + lane;
      bool cond = false;
      float iy1 = sy1[i], ix1 = sx1[i], iy2 = sy2[i], ix2 = sx2[i];
      int ic = scls[i];
      if (j < M && j > i && scls[j] == ic) {
        float jy1 = sy1[j], jx1 = sx1[j], jy2 = sy2[j], jx2 = sx2[j];
        float ai = (iy2 - iy1) * (ix2 - ix1);
        float aj = (jy2 - jy1) * (jx2 - jx1);
        float iy = fmaxf(fminf(iy2, jy2) - fmaxf(iy1, jy1), 0.f);
        float ix = fmaxf(fminf(ix2, jx2) - fmaxf(ix1, jx1), 0.f);
        float inter = iy * ix;
        float uni = fmaxf(ai + aj - inter, 1e-8f);
        cond = (inter / uni) > NMS_THRESH;
      }
      unsigned long long word = __ballot(cond);
      if (lane == 0) rows[task / W][w] = word;
    }
    __syncthreads();
    if (t < 64) {
      unsigned long long kw = (t < W) ? keepw[t] : 0ULL;
      for (int i = c0; i < c0 + R; ++i) {
        unsigned long long kwi = __shfl((long long)kw, i >> 6); // uniform lane
        if ((kwi >> (i & 63)) & 1ULL) {
          if (t < W) kw &= ~rows[i - c0][t];
        }
      }
      if (t < W) keepw[t] = kw;
    }
    __syncthreads();
  }

  // slot = popcount of kept entries ahead; write kept rows
  for (int r = t; r < M; r += NTHR) {
    unsigned long long kwme = keepw[r >> 6];
    if ((kwme >> (r & 63)) & 1ULL) {
      int slot = 0;
      for (int w = 0; w < (r >> 6); ++w) slot += __popcll(keepw[w]);
      slot += __popcll(kwme & ((1ULL << (r & 63)) - 1ULL));
      if (slot < MAX_INST) {
        float* o = out + ((size_t)b * MAX_INST + slot) * 6;
        o[0] = sy1[r]; o[1] = sx1[r]; o[2] = sy2[r]; o[3] = sx2[r];
        o[4] = (float)scls[r]; o[5] = sscr[r];
      }
    }
  }
}

extern "C" void kernel_launch(void* const* d_in, const int* in_sizes, int n_in,
                              void* d_out, int out_size, void* d_ws, size_t ws_size,
                              hipStream_t stream) {
  const float* rois    = (const float*)d_in[0];
  const float* probs   = (const float*)d_in[1];
  const float* deltas  = (const float*)d_in[2];
  const float* std_dev = (const float*)d_in[3];
  float* out = (float*)d_out;

  int*   gcnt  = (int*)d_ws;                    // 32 ints (zeroed in-kernel)
  float* glist = (float*)((char*)d_ws + 256);   // 32 x 1024 x 8 floats = 1 MB

  void* args[] = { (void*)&rois, (void*)&probs, (void*)&deltas, (void*)&std_dev,
                   (void*)&gcnt, (void*)&glist, (void*)&out };
  hipLaunchCooperativeKernel((const void*)fused_detection_kernel,
                             dim3(NBLK), dim3(NTHR), args, 0, stream);
}

// Round 5
// 104.814 us; speedup vs baseline: 2.3695x; 2.3695x over previous
//
#include <hip/hip_runtime.h>
#include <math.h>

#define BB 32
#define NN 1000
#define CC 81
#define MAX_INST 100
#define MIN_CONF 0.7f
#define NMS_THRESH 0.3f
#define MCAP 1024     // per-batch candidate list capacity (>= NN)
#define RCHUNK 192    // suppression-matrix rows per chunk
#define WMAX 16       // 64-bit words per keep row (1024/64)

// glist entry: 8 floats = {y1,x1,y2,x2,score,cls,orig_idx,pad}

// ---------------- Kernel A: one wave (64 lanes) per ROI ----------------
// Argmax over 81 classes via coalesced lane loads + shuffle reduce; lane 0
// decodes/clips the box and appends VALID candidates to a per-batch global
// list (device-scope atomic counter). Block 0 also zeroes d_out.
__global__ __launch_bounds__(256) void roi_kernel(
    const float* __restrict__ rois,      // B,N,4
    const float* __restrict__ probs,     // B,N,C
    const float* __restrict__ deltas,    // B,N,C,4
    const float* __restrict__ std_dev,   // 4
    int* __restrict__ gcnt,              // 32 counters (pre-zeroed)
    float* __restrict__ glist,           // B x MCAP x 8
    float* __restrict__ out)             // B,MAX_INST,6 (zeroed here)
{
  // zero the output slab (harness poisons d_out with 0xAA)
  if (blockIdx.x == 0) {
    float4* o4 = (float4*)out;
    for (int i = threadIdx.x; i < BB * MAX_INST * 6 / 4; i += 256)
      o4[i] = make_float4(0.f, 0.f, 0.f, 0.f);
  }

  int wg = blockIdx.x * 4 + (threadIdx.x >> 6);
  if (wg >= BB * NN) return;
  int lane = threadIdx.x & 63;

  const float* p = probs + (size_t)wg * CC;
  float v = p[lane];              // lanes 0..63 cover classes 0..63
  int   c = lane;
  if (lane + 64 < CC) {           // lanes 0..16 also cover classes 64..80
    float v2 = p[lane + 64];
    if (v2 > v) { v = v2; c = lane + 64; }   // lower class wins ties
  }
  // first-occurrence argmax: on ties keep smaller class index
  for (int off = 32; off; off >>= 1) {
    float vo = __shfl_down(v, off);
    int   co = __shfl_down(c, off);
    if (vo > v || (vo == v && co < c)) { v = vo; c = co; }
  }

  if (lane == 0 && c > 0 && v >= MIN_CONF) {
    float4 dd = *(const float4*)(deltas + ((size_t)wg * CC + c) * 4);
    float4 r4 = *(const float4*)(rois + (size_t)wg * 4);
    float dy = dd.x * std_dev[0], dx = dd.y * std_dev[1];
    float dh = dd.z * std_dev[2], dw = dd.w * std_dev[3];
    float h = r4.z - r4.x, w = r4.w - r4.y;
    float cy = r4.x + 0.5f * h + dy * h;
    float cx = r4.y + 0.5f * w + dx * w;
    h *= expf(dh); w *= expf(dw);
    float y1 = cy - 0.5f * h, x1 = cx - 0.5f * w;
    float y2 = y1 + h,        x2 = x1 + w;
    y1 = fminf(fmaxf(y1, 0.f), 1.f); x1 = fminf(fmaxf(x1, 0.f), 1.f);
    y2 = fminf(fmaxf(y2, 0.f), 1.f); x2 = fminf(fmaxf(x2, 0.f), 1.f);
    int b = wg / NN, n = wg - b * NN;
    int pos = atomicAdd(&gcnt[b], 1);          // device-scope
    float4* o = (float4*)(glist + ((size_t)b * MCAP + pos) * 8);
    o[0] = make_float4(y1, x1, y2, x2);
    o[1] = make_float4(v, (float)c, (float)n, 0.f);
  }
}

// ------------- Kernel B: one 256-thread block per batch — sort+NMS -------------
__global__ __launch_bounds__(256) void nms_kernel(
    const int* __restrict__ gcnt,
    const float* __restrict__ glist,
    float* __restrict__ out)         // B,MAX_INST,6
{
  const int b = blockIdx.x, t = threadIdx.x;

  __shared__ float cscore[MCAP];   // append-order scores
  __shared__ int   cidx[MCAP];     // append-order original indices
  __shared__ float sy1[MCAP], sx1[MCAP], sy2[MCAP], sx2[MCAP]; // sorted boxes
  __shared__ int   scls[MCAP];     // sorted classes
  __shared__ float sscr[MCAP];     // sorted scores
  __shared__ unsigned long long rows[RCHUNK][WMAX];
  __shared__ unsigned long long keepw[WMAX];

  const int M = gcnt[b];
  const int W = (M + 63) >> 6;
  const float* base = glist + (size_t)b * MCAP * 8;

  // append-order keys into LDS
  for (int e = t; e < M; e += 256) {
    const float4 s = ((const float4*)(base + (size_t)e * 8))[1];
    cscore[e] = s.x; cidx[e] = (int)s.z;
  }
  __syncthreads();

  // rank = stable-argsort position (score desc, orig idx asc); scatter sorted
  for (int e = t; e < M; e += 256) {
    const float4 a = ((const float4*)(base + (size_t)e * 8))[0];
    const float4 s = ((const float4*)(base + (size_t)e * 8))[1];
    float sc = s.x; int oi = (int)s.z;
    int r = 0;
    for (int j = 0; j < M; ++j) {
      float sj = cscore[j]; int ij = cidx[j];
      if (sj > sc || (sj == sc && ij < oi)) ++r;
    }
    sy1[r] = a.x; sx1[r] = a.y; sy2[r] = a.z; sx2[r] = a.w;
    scls[r] = (int)s.y; sscr[r] = sc;
  }
  if (t < WMAX) {
    unsigned long long kw = 0ULL;
    int nb = M - t * 64;
    if (nb > 0) kw = (nb >= 64) ? ~0ULL : ((1ULL << nb) - 1ULL);
    keepw[t] = kw;
  }
  __syncthreads();

  // chunked suppression matrix (ballot rows) + wave-serial keep propagation
  const int wv = t >> 6, lane = t & 63;
  for (int c0 = 0; c0 < M; c0 += RCHUNK) {
    int R = min(RCHUNK, M - c0);
    for (int task = wv; task < R * W; task += 4) {
      int i = c0 + task / W;
      int w = task % W;
      int j = w * 64 + lane;
      bool cond = false;
      float iy1 = sy1[i], ix1 = sx1[i], iy2 = sy2[i], ix2 = sx2[i];
      int ic = scls[i];
      if (j < M && j > i && scls[j] == ic) {
        float jy1 = sy1[j], jx1 = sx1[j], jy2 = sy2[j], jx2 = sx2[j];
        float ai = (iy2 - iy1) * (ix2 - ix1);
        float aj = (jy2 - jy1) * (jx2 - jx1);
        float iy = fmaxf(fminf(iy2, jy2) - fmaxf(iy1, jy1), 0.f);
        float ix = fmaxf(fminf(ix2, jx2) - fmaxf(ix1, jx1), 0.f);
        float inter = iy * ix;
        float uni = fmaxf(ai + aj - inter, 1e-8f);
        cond = (inter / uni) > NMS_THRESH;
      }
      unsigned long long word = __ballot(cond);
      if (lane == 0) rows[task / W][w] = word;
    }
    __syncthreads();
    if (t < 64) {
      unsigned long long kw = (t < W) ? keepw[t] : 0ULL;
      for (int i = c0; i < c0 + R; ++i) {
        unsigned long long kwi = __shfl((long long)kw, i >> 6); // uniform lane
        if ((kwi >> (i & 63)) & 1ULL) {
          if (t < W) kw &= ~rows[i - c0][t];
        }
      }
      if (t < W) keepw[t] = kw;
    }
    __syncthreads();
  }

  // slot = popcount of kept entries ahead; write kept rows
  for (int r = t; r < M; r += 256) {
    unsigned long long kwme = keepw[r >> 6];
    if ((kwme >> (r & 63)) & 1ULL) {
      int slot = 0;
      for (int w = 0; w < (r >> 6); ++w) slot += __popcll(keepw[w]);
      slot += __popcll(kwme & ((1ULL << (r & 63)) - 1ULL));
      if (slot < MAX_INST) {
        float* o = out + ((size_t)b * MAX_INST + slot) * 6;
        o[0] = sy1[r]; o[1] = sx1[r]; o[2] = sy2[r]; o[3] = sx2[r];
        o[4] = (float)scls[r]; o[5] = sscr[r];
      }
    }
  }
}

extern "C" void kernel_launch(void* const* d_in, const int* in_sizes, int n_in,
                              void* d_out, int out_size, void* d_ws, size_t ws_size,
                              hipStream_t stream) {
  const float* rois    = (const float*)d_in[0];
  const float* probs   = (const float*)d_in[1];
  const float* deltas  = (const float*)d_in[2];
  const float* std_dev = (const float*)d_in[3];
  float* out = (float*)d_out;

  int*   gcnt  = (int*)d_ws;                       // 32 ints (+pad to 128 B)
  float* glist = (float*)((char*)d_ws + 128);      // 32 x 1024 x 8 floats = 1 MB

  hipMemsetAsync(gcnt, 0, 128, stream);
  roi_kernel<<<(BB * NN + 3) / 4, 256, 0, stream>>>(rois, probs, deltas, std_dev,
                                                    gcnt, glist, out);
  nms_kernel<<<BB, 256, 0, stream>>>(gcnt, glist, out);
}